// Round 4
// baseline (1017.246 us; speedup 1.0000x reference)
//
#include <hip/hip_runtime.h>
#include <math.h>

#define DIM 32

// ---------------- degree (weighted) + in-degree count ----------------
__global__ void deg_cnt_kernel(const int* __restrict__ col, const float* __restrict__ w,
                               float* __restrict__ deg, int* __restrict__ cnt, int E) {
    int e = blockIdx.x * blockDim.x + threadIdx.x;
    if (e < E) {
        int c = col[e];
        atomicAdd(&deg[c], w[e]);
        atomicAdd(&cnt[c], 1);
    }
}

// dinv = rsqrt(deg+1), in place
__global__ void dinv_kernel(float* __restrict__ deg, int N) {
    int n = blockIdx.x * blockDim.x + threadIdx.x;
    if (n < N) deg[n] = rsqrtf(deg[n] + 1.0f);
}

// ---------------- scan: per-block exclusive scan of cnt -> ptr, block totals -> bsum ----------------
__global__ void scan_block_kernel(const int* __restrict__ cnt, int* __restrict__ ptr,
                                  int* __restrict__ bsum, int N) {
    __shared__ int s[256];
    int i = blockIdx.x * 256 + threadIdx.x;
    int v = (i < N) ? cnt[i] : 0;
    s[threadIdx.x] = v;
    __syncthreads();
#pragma unroll
    for (int off = 1; off < 256; off <<= 1) {
        int t = (threadIdx.x >= off) ? s[threadIdx.x - off] : 0;
        __syncthreads();
        s[threadIdx.x] += t;
        __syncthreads();
    }
    if (i < N) ptr[i] = s[threadIdx.x] - v;  // exclusive
    if (threadIdx.x == 255) bsum[blockIdx.x] = s[255];
}

// serial scan of block totals (nb=625, trivial)
__global__ void scan_tops_kernel(int* __restrict__ bsum, int* __restrict__ ptr, int nb, int N) {
    if (blockIdx.x == 0 && threadIdx.x == 0) {
        int run = 0;
        for (int b = 0; b < nb; b++) { int t = bsum[b]; bsum[b] = run; run += t; }
        ptr[N] = run;  // == E
    }
}

// add block offsets; also init cursor (reuses cnt buffer)
__global__ void scan_add_kernel(int* __restrict__ ptr, const int* __restrict__ bsum,
                                int* __restrict__ cursor, int N) {
    int i = blockIdx.x * blockDim.x + threadIdx.x;
    if (i < N) {
        int p = ptr[i] + bsum[i >> 8];
        ptr[i] = p;
        cursor[i] = p;
    }
}

// ---------------- counting-sort edges by col; precompute norm once ----------------
__global__ void sort_kernel(const int* __restrict__ row, const int* __restrict__ col,
                            const float* __restrict__ w, const float* __restrict__ dinv,
                            int* __restrict__ cursor, float2* __restrict__ edat, int E) {
    int e = blockIdx.x * blockDim.x + threadIdx.x;
    if (e >= E) return;
    int r = row[e], c = col[e];
    float nm = dinv[r] * w[e] * dinv[c];
    int pos = atomicAdd(&cursor[c], 1);
    edat[pos] = make_float2(__int_as_float(r), nm);
}

// ---------------- pre-MLP (2 layers) + xw0 = h @ Wg0, fused via shuffle matmul ----------------
__global__ void premlp_xw_kernel(const float* __restrict__ x,
                                 const float* __restrict__ W0, const float* __restrict__ b0,
                                 const float* __restrict__ W1, const float* __restrict__ b1,
                                 const float* __restrict__ Wg, float* __restrict__ xw0, int N) {
    int tid = blockIdx.x * blockDim.x + threadIdx.x;
    if (tid >= N * DIM) return;
    int n = tid >> 5, d = tid & 31;
    float xv = x[n];
    float acc = b1[d];
#pragma unroll
    for (int k = 0; k < DIM; k++) {
        float h0 = fmaxf(xv * W0[k] + b0[k], 0.0f);
        acc += h0 * W1[k * DIM + d];
    }
    float h = fmaxf(acc, 0.0f);
    float o = 0.0f;
#pragma unroll
    for (int k = 0; k < DIM; k++) {
        float hk = __shfl(h, k, 32);
        o += hk * Wg[k * DIM + d];
    }
    xw0[tid] = o;
}

// ---------------- fused CSR gather + (next-xw | pool) ----------------
// agg = b[d] + xw[n]*dinv^2 + sum_e norm*xw[row];  h = relu(agg)
// Inner loop: lane-uniform broadcast loads of edat (no shuffles) in 16-wide
// register batches -> 16 independent edat loads, then 16 independent row
// gathers in flight per thread (latency hiding via MLP, not occupancy).
template <bool FUSE_POOL>
__global__ void gather_kernel(const float* __restrict__ xw, const float2* __restrict__ edat,
                              const int* __restrict__ ptr, const float* __restrict__ dinv,
                              const float* __restrict__ b, const float* __restrict__ Wn,
                              const int* __restrict__ batch,
                              float* __restrict__ out, float* __restrict__ sums,
                              float* __restrict__ gcnt, int N) {
    int tid = blockIdx.x * blockDim.x + threadIdx.x;
    if (tid >= N * DIM) return;
    int n = tid >> 5, d = tid & 31;
    int s = ptr[n], epos = ptr[n + 1];
    float di = dinv[n];
    float acc0 = xw[tid] * di * di + b[d];
    float acc1 = 0.0f;
    for (int base = s; base < epos; base += 16) {
        // phase 1: 16 independent edge-record loads (lane-uniform -> broadcast)
        float2 v[16];
#pragma unroll
        for (int i = 0; i < 16; i++) {
            int idx = base + i;
            v[i] = edat[(idx < epos) ? idx : base];  // clamp: valid line, masked below
        }
        // phase 2: 16 independent row gathers
        float xv[16];
#pragma unroll
        for (int i = 0; i < 16; i++) {
            xv[i] = xw[__float_as_int(v[i].x) * DIM + d];
        }
        // phase 3: FMAs (2 chains)
#pragma unroll
        for (int i = 0; i < 16; i++) {
            float nm = (base + i < epos) ? v[i].y : 0.0f;
            if (i & 1) acc1 += nm * xv[i];
            else       acc0 += nm * xv[i];
        }
    }
    float h = fmaxf(acc0 + acc1, 0.0f);
    if (FUSE_POOL) {
        int g = batch[n];
        atomicAdd(&sums[g * DIM + d], h);
        if (d == 0) atomicAdd(&gcnt[g], 1.0f);
    } else {
        float o = 0.0f;
#pragma unroll
        for (int k = 0; k < DIM; k++) {
            float hk = __shfl(h, k, 32);
            o += hk * Wn[k * DIM + d];
        }
        out[tid] = o;
    }
}

// ---------------- post-MLP: relu(g@W0+b0) @ W1 + b1 -> sigmoid ----------------
__global__ void postmlp_kernel(const float* __restrict__ sums, const float* __restrict__ gcnt,
                               const float* __restrict__ W0, const float* __restrict__ b0,
                               const float* __restrict__ W1, const float* __restrict__ b1,
                               float* __restrict__ out, int G) {
    int g = blockIdx.x * blockDim.x + threadIdx.x;
    if (g >= G) return;
    float c = fmaxf(gcnt[g], 1.0f);
    float inv = 1.0f / c;
    float gv[DIM];
#pragma unroll
    for (int k = 0; k < DIM; k++) gv[k] = sums[g * DIM + k] * inv;
    float acc = b1[0];
#pragma unroll
    for (int j = 0; j < DIM; j++) {
        float p = b0[j];
#pragma unroll
        for (int k = 0; k < DIM; k++) p += gv[k] * W0[k * DIM + j];
        p = fmaxf(p, 0.0f);
        acc += p * W1[j];
    }
    out[g] = 1.0f / (1.0f + expf(-acc));
}

extern "C" void kernel_launch(void* const* d_in, const int* in_sizes, int n_in,
                              void* d_out, int out_size, void* d_ws, size_t ws_size,
                              hipStream_t stream) {
    const float* x   = (const float*)d_in[0];
    const int*   ei  = (const int*)d_in[1];
    const float* ew  = (const float*)d_in[2];
    const int*   bat = (const int*)d_in[3];
    const float* Wpre0 = (const float*)d_in[4];
    const float* bpre0 = (const float*)d_in[5];
    const float* Wpre1 = (const float*)d_in[6];
    const float* bpre1 = (const float*)d_in[7];
    const float* Wg[3]  = {(const float*)d_in[8],  (const float*)d_in[10], (const float*)d_in[12]};
    const float* bg[3]  = {(const float*)d_in[9],  (const float*)d_in[11], (const float*)d_in[13]};
    const float* Wpost0 = (const float*)d_in[14];
    const float* bpost0 = (const float*)d_in[15];
    const float* Wpost1 = (const float*)d_in[16];
    const float* bpost1 = (const float*)d_in[17];
    float* out = (float*)d_out;

    const int N = in_sizes[0];       // 160000
    const int E = in_sizes[2];       // 2560000
    const int G = out_size;          // 1024
    const int nb = (N + 255) / 256;  // scan blocks

    const int* row = ei;
    const int* col = ei + E;

    // ---- workspace layout (4-byte units) ----
    float* ws = (float*)d_ws;
    size_t nd = (size_t)N * DIM;
    float*  bufA  = ws;                          // nd
    float*  bufB  = bufA + nd;                   // nd
    float*  dinv  = bufB + nd;                   // N    (deg -> dinv in place)
    int*    cnt   = (int*)(dinv + N);            // N    (counts -> cursor)
    float*  sums  = (float*)(cnt + N);           // G*DIM
    float*  gcnt  = sums + (size_t)G * DIM;      // G
    int*    ptr   = (int*)(gcnt + G);            // N+2 (pad to even)
    int*    bsum  = ptr + (N + 2);               // nb (pad to even)
    float2* edat  = (float2*)(bsum + ((nb + 1) & ~1)); // E * 8B

    // zero the atomic accumulators: dinv(deg) | cnt | sums | gcnt  (contiguous)
    hipMemsetAsync(dinv, 0, sizeof(float) * ((size_t)N + N + (size_t)G * DIM + G), stream);

    const int B = 256;
    int ndThreads = N * DIM;

    // degree + count
    deg_cnt_kernel<<<(E + B - 1) / B, B, 0, stream>>>(col, ew, dinv, cnt, E);
    dinv_kernel<<<(N + B - 1) / B, B, 0, stream>>>(dinv, N);

    // CSR build: scan + sort (norm precomputed once)
    scan_block_kernel<<<nb, 256, 0, stream>>>(cnt, ptr, bsum, N);
    scan_tops_kernel<<<1, 64, 0, stream>>>(bsum, ptr, nb, N);
    scan_add_kernel<<<(N + B - 1) / B, B, 0, stream>>>(ptr, bsum, cnt, N);
    sort_kernel<<<(E + B - 1) / B, B, 0, stream>>>(row, col, ew, dinv, cnt, edat, E);

    // pre-MLP + xw0 -> bufB
    premlp_xw_kernel<<<(ndThreads + B - 1) / B, B, 0, stream>>>(
        x, Wpre0, bpre0, Wpre1, bpre1, Wg[0], bufB, N);

    // L0: gather(xw0) + xw1  : bufB -> bufA   (uses bg[0], Wg[1])
    gather_kernel<false><<<(ndThreads + B - 1) / B, B, 0, stream>>>(
        bufB, edat, ptr, dinv, bg[0], Wg[1], bat, bufA, sums, gcnt, N);
    // L1: gather(xw1) + xw2  : bufA -> bufB   (uses bg[1], Wg[2])
    gather_kernel<false><<<(ndThreads + B - 1) / B, B, 0, stream>>>(
        bufA, edat, ptr, dinv, bg[1], Wg[2], bat, bufB, sums, gcnt, N);
    // L2: gather(xw2) + pool (uses bg[2])
    gather_kernel<true><<<(ndThreads + B - 1) / B, B, 0, stream>>>(
        bufB, edat, ptr, dinv, bg[2], nullptr, bat, nullptr, sums, gcnt, N);

    // post-MLP
    postmlp_kernel<<<(G + B - 1) / B, B, 0, stream>>>(sums, gcnt, Wpost0, bpost0, Wpost1, bpost1, out, G);
}

// Round 5
// 939.142 us; speedup vs baseline: 1.0832x; 1.0832x over previous
//
#include <hip/hip_runtime.h>
#include <math.h>

#define DIM 32

__device__ __forceinline__ void async_gather4(const float* g, float* l) {
    __builtin_amdgcn_global_load_lds(
        (const __attribute__((address_space(1))) void*)g,
        (__attribute__((address_space(3))) void*)l, 4, 0, 0);
}

// ---------------- fused degree+count: one u64 atomic per edge ----------------
// packed[c] += (1<<40) | (u64)(w * 2^32)   (count in [63:40], w-sum fixed-point in [39:0])
__global__ void deg_cnt_kernel(const int* __restrict__ col, const float* __restrict__ w,
                               unsigned long long* __restrict__ packed, int E) {
    int e = blockIdx.x * blockDim.x + threadIdx.x;
    if (e < E) {
        unsigned long long wf = (unsigned long long)(w[e] * 4294967296.0f);
        atomicAdd(&packed[col[e]], (1ull << 40) | wf);
    }
}

__global__ void unpack_kernel(const unsigned long long* __restrict__ packed,
                              float* __restrict__ dinv, int* __restrict__ cnt, int N) {
    int n = blockIdx.x * blockDim.x + threadIdx.x;
    if (n < N) {
        unsigned long long p = packed[n];
        cnt[n] = (int)(p >> 40);
        float deg = (float)((double)(p & ((1ull << 40) - 1)) * (1.0 / 4294967296.0));
        dinv[n] = rsqrtf(deg + 1.0f);
    }
}

// ---------------- scan: per-block exclusive scan of cnt -> ptr, block totals -> bsum ----------------
__global__ void scan_block_kernel(const int* __restrict__ cnt, int* __restrict__ ptr,
                                  int* __restrict__ bsum, int N) {
    __shared__ int s[256];
    int i = blockIdx.x * 256 + threadIdx.x;
    int v = (i < N) ? cnt[i] : 0;
    s[threadIdx.x] = v;
    __syncthreads();
#pragma unroll
    for (int off = 1; off < 256; off <<= 1) {
        int t = (threadIdx.x >= off) ? s[threadIdx.x - off] : 0;
        __syncthreads();
        s[threadIdx.x] += t;
        __syncthreads();
    }
    if (i < N) ptr[i] = s[threadIdx.x] - v;  // exclusive
    if (threadIdx.x == 255) bsum[blockIdx.x] = s[255];
}

__global__ void scan_tops_kernel(int* __restrict__ bsum, int* __restrict__ ptr, int nb, int N) {
    if (blockIdx.x == 0 && threadIdx.x == 0) {
        int run = 0;
        for (int b = 0; b < nb; b++) { int t = bsum[b]; bsum[b] = run; run += t; }
        ptr[N] = run;  // == E
    }
}

__global__ void scan_add_kernel(int* __restrict__ ptr, const int* __restrict__ bsum,
                                int* __restrict__ cursor, int N) {
    int i = blockIdx.x * blockDim.x + threadIdx.x;
    if (i < N) {
        int p = ptr[i] + bsum[i >> 8];
        ptr[i] = p;
        cursor[i] = p;
    }
}

// ---------------- counting-sort edges by col; precompute norm once ----------------
__global__ void sort_kernel(const int* __restrict__ row, const int* __restrict__ col,
                            const float* __restrict__ w, const float* __restrict__ dinv,
                            int* __restrict__ cursor, float2* __restrict__ edat, int E) {
    int e = blockIdx.x * blockDim.x + threadIdx.x;
    if (e >= E) return;
    int r = row[e], c = col[e];
    float nm = dinv[r] * w[e] * dinv[c];
    int pos = atomicAdd(&cursor[c], 1);
    edat[pos] = make_float2(__int_as_float(r), nm);
}

// ---------------- pre-MLP (2 layers) + xw0 = h @ Wg0, fused via shuffle matmul ----------------
__global__ void premlp_xw_kernel(const float* __restrict__ x,
                                 const float* __restrict__ W0, const float* __restrict__ b0,
                                 const float* __restrict__ W1, const float* __restrict__ b1,
                                 const float* __restrict__ Wg, float* __restrict__ xw0, int N) {
    int tid = blockIdx.x * blockDim.x + threadIdx.x;
    if (tid >= N * DIM) return;
    int n = tid >> 5, d = tid & 31;
    float xv = x[n];
    float acc = b1[d];
#pragma unroll
    for (int k = 0; k < DIM; k++) {
        float h0 = fmaxf(xv * W0[k] + b0[k], 0.0f);
        acc += h0 * W1[k * DIM + d];
    }
    float h = fmaxf(acc, 0.0f);
    float o = 0.0f;
#pragma unroll
    for (int k = 0; k < DIM; k++) {
        float hk = __shfl(h, k, 32);
        o += hk * Wg[k * DIM + d];
    }
    xw0[tid] = o;
}

// ---------------- fused CSR gather via global_load_lds pipeline ----------------
// One wave handles 2 nodes (half-wave each). Per 16-edge chunk:
//   coalesced edat load -> bpermute (row,nm) -> 16 global_load_lds (no VGPR results,
//   all in flight) -> s_waitcnt vmcnt(0) -> 16 ds_read + fma.
template <bool FUSE_POOL>
__global__ void gather_kernel(const float* __restrict__ xw, const float2* __restrict__ edat,
                              const int* __restrict__ ptr, const float* __restrict__ dinv,
                              const float* __restrict__ b, const float* __restrict__ Wn,
                              const int* __restrict__ batch,
                              float* __restrict__ out, float* __restrict__ sums,
                              float* __restrict__ gcnt, int N) {
    __shared__ float lds[4 * 16 * 64];  // 4 waves x 16 slots x 64 lanes = 16 KB
    int gw = (blockIdx.x * blockDim.x + threadIdx.x) >> 6;  // global wave id
    int l = threadIdx.x & 63;
    int half = l >> 5, d = l & 31;
    int node = gw * 2 + half;
    bool nvalid = node < N;
    int nc = nvalid ? node : N - 1;
    int e0 = ptr[nc], e1 = ptr[nc + 1];
    int deg = e1 - e0;
    int odeg = __shfl(deg, l ^ 32, 64);
    int maxdeg = max(deg, odeg);  // wave-uniform
    float di = dinv[nc];
    float acc = xw[(size_t)nc * DIM + d] * di * di + b[d];
    float* wbase = &lds[(threadIdx.x >> 6) * (16 * 64)];

    for (int base = 0; base < maxdeg; base += 16) {
        int idx = e0 + base + (l & 15);
        idx = max(min(idx, e1 - 1), 0);
        float2 rec = edat[idx];  // lanes 0-15: node0 recs, lanes 32-47: node1 recs
        int cmax = min(16, maxdeg - base);
        float nmv[16];
#pragma unroll
        for (int j = 0; j < 16; j++) {
            if (j < cmax) {
                int src = half * 32 + j;
                int ri = __float_as_int(__shfl(rec.x, src, 64));
                float nm = __shfl(rec.y, src, 64);
                bool v = (base + j) < deg;
                nmv[j] = v ? nm : 0.0f;
                ri = v ? ri : 0;
                async_gather4(xw + (size_t)ri * DIM + d, wbase + j * 64);
            }
        }
        __builtin_amdgcn_s_waitcnt(0x0F70);  // vmcnt(0) only
        __builtin_amdgcn_sched_barrier(0);
#pragma unroll
        for (int j = 0; j < 16; j++) {
            if (j < cmax) acc += nmv[j] * wbase[j * 64 + l];
        }
    }
    float h = fmaxf(acc, 0.0f);
    if (FUSE_POOL) {
        if (nvalid) {
            int g = batch[nc];
            atomicAdd(&sums[g * DIM + d], h);
            if (d == 0) atomicAdd(&gcnt[g], 1.0f);
        }
    } else {
        float o = 0.0f;
#pragma unroll
        for (int k = 0; k < DIM; k++) {
            float hk = __shfl(h, half * 32 + k, 64);  // from own half's lane k
            o += hk * Wn[k * DIM + d];
        }
        if (nvalid) out[(size_t)nc * DIM + d] = o;
    }
}

// ---------------- post-MLP: relu(g@W0+b0) @ W1 + b1 -> sigmoid ----------------
__global__ void postmlp_kernel(const float* __restrict__ sums, const float* __restrict__ gcnt,
                               const float* __restrict__ W0, const float* __restrict__ b0,
                               const float* __restrict__ W1, const float* __restrict__ b1,
                               float* __restrict__ out, int G) {
    int g = blockIdx.x * blockDim.x + threadIdx.x;
    if (g >= G) return;
    float c = fmaxf(gcnt[g], 1.0f);
    float inv = 1.0f / c;
    float gv[DIM];
#pragma unroll
    for (int k = 0; k < DIM; k++) gv[k] = sums[g * DIM + k] * inv;
    float acc = b1[0];
#pragma unroll
    for (int j = 0; j < DIM; j++) {
        float p = b0[j];
#pragma unroll
        for (int k = 0; k < DIM; k++) p += gv[k] * W0[k * DIM + j];
        p = fmaxf(p, 0.0f);
        acc += p * W1[j];
    }
    out[g] = 1.0f / (1.0f + expf(-acc));
}

extern "C" void kernel_launch(void* const* d_in, const int* in_sizes, int n_in,
                              void* d_out, int out_size, void* d_ws, size_t ws_size,
                              hipStream_t stream) {
    const float* x   = (const float*)d_in[0];
    const int*   ei  = (const int*)d_in[1];
    const float* ew  = (const float*)d_in[2];
    const int*   bat = (const int*)d_in[3];
    const float* Wpre0 = (const float*)d_in[4];
    const float* bpre0 = (const float*)d_in[5];
    const float* Wpre1 = (const float*)d_in[6];
    const float* bpre1 = (const float*)d_in[7];
    const float* Wg[3]  = {(const float*)d_in[8],  (const float*)d_in[10], (const float*)d_in[12]};
    const float* bg[3]  = {(const float*)d_in[9],  (const float*)d_in[11], (const float*)d_in[13]};
    const float* Wpost0 = (const float*)d_in[14];
    const float* bpost0 = (const float*)d_in[15];
    const float* Wpost1 = (const float*)d_in[16];
    const float* bpost1 = (const float*)d_in[17];
    float* out = (float*)d_out;

    const int N = in_sizes[0];       // 160000
    const int E = in_sizes[2];       // 2560000
    const int G = out_size;          // 1024
    const int nb = (N + 255) / 256;

    const int* row = ei;
    const int* col = ei + E;

    // ---- workspace layout (4-byte units; packed needs 8B alignment) ----
    float* ws = (float*)d_ws;
    size_t nd = (size_t)N * DIM;
    float*  bufA   = ws;                               // nd
    float*  bufB   = bufA + nd;                        // nd
    unsigned long long* packed = (unsigned long long*)(bufB + nd);  // N u64 (nd even -> 8B aligned)
    float*  sums   = (float*)(packed + N);             // G*DIM
    float*  gcnt   = sums + (size_t)G * DIM;           // G
    float*  dinv   = gcnt + G;                         // N
    int*    cnt    = (int*)(dinv + N);                 // N (counts -> cursor)
    int*    ptr    = cnt + N;                          // N+2
    int*    bsum   = ptr + (N + 2);                    // nb
    float2* edat   = (float2*)(bsum + ((nb + 1) & ~1)); // (E+1) * 8B

    // zero block: packed | sums | gcnt (contiguous)
    hipMemsetAsync(packed, 0, sizeof(unsigned long long) * N + sizeof(float) * ((size_t)G * DIM + G), stream);

    const int B = 256;
    int ndThreads = N * DIM;

    // degree+count (fused u64 atomic), unpack to dinv + cnt
    deg_cnt_kernel<<<(E + B - 1) / B, B, 0, stream>>>(col, ew, packed, E);
    unpack_kernel<<<(N + B - 1) / B, B, 0, stream>>>(packed, dinv, cnt, N);

    // CSR build: scan + sort (norm precomputed once)
    scan_block_kernel<<<nb, 256, 0, stream>>>(cnt, ptr, bsum, N);
    scan_tops_kernel<<<1, 64, 0, stream>>>(bsum, ptr, nb, N);
    scan_add_kernel<<<(N + B - 1) / B, B, 0, stream>>>(ptr, bsum, cnt, N);
    sort_kernel<<<(E + B - 1) / B, B, 0, stream>>>(row, col, ew, dinv, cnt, edat, E);

    // pre-MLP + xw0 -> bufB
    premlp_xw_kernel<<<(ndThreads + B - 1) / B, B, 0, stream>>>(
        x, Wpre0, bpre0, Wpre1, bpre1, Wg[0], bufB, N);

    // gather grid: one wave per 2 nodes
    int nWaves = (N + 1) / 2;
    int gBlocks = (nWaves + 3) / 4;

    // L0: gather(xw0) + xw1 : bufB -> bufA
    gather_kernel<false><<<gBlocks, 256, 0, stream>>>(
        bufB, edat, ptr, dinv, bg[0], Wg[1], bat, bufA, sums, gcnt, N);
    // L1: gather(xw1) + xw2 : bufA -> bufB
    gather_kernel<false><<<gBlocks, 256, 0, stream>>>(
        bufA, edat, ptr, dinv, bg[1], Wg[2], bat, bufB, sums, gcnt, N);
    // L2: gather(xw2) + pool
    gather_kernel<true><<<gBlocks, 256, 0, stream>>>(
        bufB, edat, ptr, dinv, bg[2], nullptr, bat, nullptr, sums, gcnt, N);

    // post-MLP
    postmlp_kernel<<<(G + B - 1) / B, B, 0, stream>>>(sums, gcnt, Wpost0, bpost0, Wpost1, bpost1, out, G);
}

// Round 6
// 888.671 us; speedup vs baseline: 1.1447x; 1.0568x over previous
//
#include <hip/hip_runtime.h>
#include <math.h>

#define DIM 32

__device__ __forceinline__ void async_gather4(const void* g, void* l) {
    __builtin_amdgcn_global_load_lds(
        (const __attribute__((address_space(1))) void*)g,
        (__attribute__((address_space(3))) void*)l, 4, 0, 0);
}

__device__ __forceinline__ unsigned short f2bf(float f) {
    unsigned u = __float_as_uint(f);
    u = (u + 0x7FFF + ((u >> 16) & 1)) >> 16;  // RNE
    return (unsigned short)u;
}
__device__ __forceinline__ float bf2f(unsigned short u) {
    return __uint_as_float(((unsigned)u) << 16);
}

// ---------------- fused degree+count: one u64 atomic per edge ----------------
__global__ void deg_cnt_kernel(const int* __restrict__ col, const float* __restrict__ w,
                               unsigned long long* __restrict__ packed, int E) {
    int e = blockIdx.x * blockDim.x + threadIdx.x;
    if (e < E) {
        unsigned long long wf = (unsigned long long)(w[e] * 4294967296.0f);
        atomicAdd(&packed[col[e]], (1ull << 40) | wf);
    }
}

__global__ void unpack_kernel(const unsigned long long* __restrict__ packed,
                              float* __restrict__ dinv, int* __restrict__ cnt, int N) {
    int n = blockIdx.x * blockDim.x + threadIdx.x;
    if (n < N) {
        unsigned long long p = packed[n];
        cnt[n] = (int)(p >> 40);
        float deg = (float)((double)(p & ((1ull << 40) - 1)) * (1.0 / 4294967296.0));
        dinv[n] = rsqrtf(deg + 1.0f);
    }
}

// ---------------- scan ----------------
__global__ void scan_block_kernel(const int* __restrict__ cnt, int* __restrict__ ptr,
                                  int* __restrict__ bsum, int N) {
    __shared__ int s[256];
    int i = blockIdx.x * 256 + threadIdx.x;
    int v = (i < N) ? cnt[i] : 0;
    s[threadIdx.x] = v;
    __syncthreads();
#pragma unroll
    for (int off = 1; off < 256; off <<= 1) {
        int t = (threadIdx.x >= off) ? s[threadIdx.x - off] : 0;
        __syncthreads();
        s[threadIdx.x] += t;
        __syncthreads();
    }
    if (i < N) ptr[i] = s[threadIdx.x] - v;
    if (threadIdx.x == 255) bsum[blockIdx.x] = s[255];
}

__global__ void scan_tops_kernel(int* __restrict__ bsum, int* __restrict__ ptr, int nb, int N) {
    if (blockIdx.x == 0 && threadIdx.x == 0) {
        int run = 0;
        for (int b = 0; b < nb; b++) { int t = bsum[b]; bsum[b] = run; run += t; }
        ptr[N] = run;
    }
}

__global__ void scan_add_kernel(int* __restrict__ ptr, const int* __restrict__ bsum,
                                int* __restrict__ cursor, int N) {
    int i = blockIdx.x * blockDim.x + threadIdx.x;
    if (i < N) {
        int p = ptr[i] + bsum[i >> 8];
        ptr[i] = p;
        cursor[i] = p;
    }
}

// ---------------- counting-sort edges by col; precompute norm once ----------------
__global__ void sort_kernel(const int* __restrict__ row, const int* __restrict__ col,
                            const float* __restrict__ w, const float* __restrict__ dinv,
                            int* __restrict__ cursor, float2* __restrict__ edat, int E) {
    int e = blockIdx.x * blockDim.x + threadIdx.x;
    if (e >= E) return;
    int r = row[e], c = col[e];
    float nm = dinv[r] * w[e] * dinv[c];
    int pos = atomicAdd(&cursor[c], 1);
    edat[pos] = make_float2(__int_as_float(r), nm);
}

// ---------------- pre-MLP + xw0 (bf16 out) ----------------
__global__ void premlp_xw_kernel(const float* __restrict__ x,
                                 const float* __restrict__ W0, const float* __restrict__ b0,
                                 const float* __restrict__ W1, const float* __restrict__ b1,
                                 const float* __restrict__ Wg, unsigned short* __restrict__ xw0, int N) {
    int tid = blockIdx.x * blockDim.x + threadIdx.x;
    if (tid >= N * DIM) return;
    int n = tid >> 5, d = tid & 31;
    float xv = x[n];
    float acc = b1[d];
#pragma unroll
    for (int k = 0; k < DIM; k++) {
        float h0 = fmaxf(xv * W0[k] + b0[k], 0.0f);
        acc += h0 * W1[k * DIM + d];
    }
    float h = fmaxf(acc, 0.0f);
    float o = 0.0f;
#pragma unroll
    for (int k = 0; k < DIM; k++) {
        float hk = __shfl(h, k, 32);
        o += hk * Wg[k * DIM + d];
    }
    xw0[tid] = f2bf(o);
}

// ---------------- fused CSR gather (bf16 features) + (next-xw | pool) ----------------
// One wave = 2 nodes. Per 16-edge chunk: 1 coalesced edat load; 8 async ops,
// each fetching 2 edges x 2 nodes (16 lanes per 64-B bf16 row); drain; 16 LDS
// u16 reads + fp32 FMA with shuffled norms.
template <bool FUSE_POOL>
__global__ void gather_kernel(const unsigned short* __restrict__ xwb, const float2* __restrict__ edat,
                              const int* __restrict__ ptr, const float* __restrict__ dinv,
                              const float* __restrict__ b, const float* __restrict__ Wn,
                              const int* __restrict__ batch,
                              unsigned short* __restrict__ outb, float* __restrict__ sums,
                              float* __restrict__ gcnt, int N) {
    __shared__ float lds[4 * 8 * 64];  // 4 waves x 8 slots x 256 B = 8 KB
    int gw = (blockIdx.x * blockDim.x + threadIdx.x) >> 6;
    int l = threadIdx.x & 63;
    int half = l >> 5, d = l & 31;
    int node = gw * 2 + half;
    bool nvalid = node < N;
    int nc = nvalid ? node : N - 1;
    int e0 = ptr[nc], e1 = ptr[nc + 1];
    int deg = e1 - e0;
    int odeg = __shfl(deg, l ^ 32, 64);
    int maxdeg = max(deg, odeg);  // wave-uniform
    float di = dinv[nc];
    float acc = bf2f(xwb[(size_t)nc * DIM + d]) * di * di + b[d];
    float* wbase = &lds[(threadIdx.x >> 6) * (8 * 64)];
    int bit = (l >> 4) & 1;       // which of the edge pair this lane group fetches

    for (int base = 0; base < maxdeg; base += 16) {
        int idx = e0 + base + (l & 15);
        idx = max(min(idx, e1 - 1), 0);
        float2 rec = edat[idx];   // lanes 0-15: node0 recs, 32-47: node1 recs
        int cmax = min(16, maxdeg - base);
        // issue async gathers: op k covers edges 2k (bit=0) and 2k+1 (bit=1)
#pragma unroll
        for (int k = 0; k < 8; k++) {
            if (2 * k < cmax) {
                int e = 2 * k + bit;
                int ri = __float_as_int(__shfl(rec.x, (l & 32) + e, 64));
                bool v = (base + e) < deg;
                ri = v ? ri : 0;
                // lane group of 16 fetches one 64-B bf16 row: 4 B = 2 dims per lane
                async_gather4(xwb + (size_t)ri * DIM + (l & 15) * 2, wbase + k * 64);
            }
        }
        // norms during the drain window
        float nmv[16];
#pragma unroll
        for (int e = 0; e < 16; e++) {
            if (e < cmax) {
                float nm = __shfl(rec.y, (l & 32) + e, 64);
                nmv[e] = ((base + e) < deg) ? nm : 0.0f;
            }
        }
        __builtin_amdgcn_s_waitcnt(0x0F70);  // vmcnt(0)
        const unsigned short* wb16 = (const unsigned short*)wbase;
#pragma unroll
        for (int e = 0; e < 16; e++) {
            if (e < cmax) {
                int k = e >> 1, eb = e & 1;
                unsigned short u = wb16[k * 128 + half * 64 + eb * 32 + d];
                acc += nmv[e] * bf2f(u);
            }
        }
    }
    float h = fmaxf(acc, 0.0f);
    if (FUSE_POOL) {
        if (nvalid) {
            int g = batch[nc];
            atomicAdd(&sums[g * DIM + d], h);
            if (d == 0) atomicAdd(&gcnt[g], 1.0f);
        }
    } else {
        float o = 0.0f;
#pragma unroll
        for (int k = 0; k < DIM; k++) {
            float hk = __shfl(h, half * 32 + k, 64);
            o += hk * Wn[k * DIM + d];
        }
        if (nvalid) outb[(size_t)nc * DIM + d] = f2bf(o);
    }
}

// ---------------- post-MLP ----------------
__global__ void postmlp_kernel(const float* __restrict__ sums, const float* __restrict__ gcnt,
                               const float* __restrict__ W0, const float* __restrict__ b0,
                               const float* __restrict__ W1, const float* __restrict__ b1,
                               float* __restrict__ out, int G) {
    int g = blockIdx.x * blockDim.x + threadIdx.x;
    if (g >= G) return;
    float c = fmaxf(gcnt[g], 1.0f);
    float inv = 1.0f / c;
    float gv[DIM];
#pragma unroll
    for (int k = 0; k < DIM; k++) gv[k] = sums[g * DIM + k] * inv;
    float acc = b1[0];
#pragma unroll
    for (int j = 0; j < DIM; j++) {
        float p = b0[j];
#pragma unroll
        for (int k = 0; k < DIM; k++) p += gv[k] * W0[k * DIM + j];
        p = fmaxf(p, 0.0f);
        acc += p * W1[j];
    }
    out[g] = 1.0f / (1.0f + expf(-acc));
}

extern "C" void kernel_launch(void* const* d_in, const int* in_sizes, int n_in,
                              void* d_out, int out_size, void* d_ws, size_t ws_size,
                              hipStream_t stream) {
    const float* x   = (const float*)d_in[0];
    const int*   ei  = (const int*)d_in[1];
    const float* ew  = (const float*)d_in[2];
    const int*   bat = (const int*)d_in[3];
    const float* Wpre0 = (const float*)d_in[4];
    const float* bpre0 = (const float*)d_in[5];
    const float* Wpre1 = (const float*)d_in[6];
    const float* bpre1 = (const float*)d_in[7];
    const float* Wg[3]  = {(const float*)d_in[8],  (const float*)d_in[10], (const float*)d_in[12]};
    const float* bg[3]  = {(const float*)d_in[9],  (const float*)d_in[11], (const float*)d_in[13]};
    const float* Wpost0 = (const float*)d_in[14];
    const float* bpost0 = (const float*)d_in[15];
    const float* Wpost1 = (const float*)d_in[16];
    const float* bpost1 = (const float*)d_in[17];
    float* out = (float*)d_out;

    const int N = in_sizes[0];       // 160000
    const int E = in_sizes[2];       // 2560000
    const int G = out_size;          // 1024
    const int nb = (N + 255) / 256;

    const int* row = ei;
    const int* col = ei + E;

    // ---- workspace layout ----
    unsigned short* bufA = (unsigned short*)d_ws;      // nd bf16
    size_t nd = (size_t)N * DIM;
    unsigned short* bufB = bufA + nd;                  // nd bf16
    unsigned long long* packed = (unsigned long long*)(bufB + nd);  // N u64 (4*nd bytes offset, 8B aligned)
    float*  sums   = (float*)(packed + N);             // G*DIM
    float*  gcnt   = sums + (size_t)G * DIM;           // G
    float*  dinv   = gcnt + G;                         // N
    int*    cnt    = (int*)(dinv + N);                 // N
    int*    ptr    = cnt + N;                          // N+2
    int*    bsum   = ptr + (N + 2);                    // nb
    float2* edat   = (float2*)(bsum + ((nb + 1) & ~1)); // E * 8B

    hipMemsetAsync(packed, 0, sizeof(unsigned long long) * N + sizeof(float) * ((size_t)G * DIM + G), stream);

    const int B = 256;
    int ndThreads = N * DIM;

    deg_cnt_kernel<<<(E + B - 1) / B, B, 0, stream>>>(col, ew, packed, E);
    unpack_kernel<<<(N + B - 1) / B, B, 0, stream>>>(packed, dinv, cnt, N);

    scan_block_kernel<<<nb, 256, 0, stream>>>(cnt, ptr, bsum, N);
    scan_tops_kernel<<<1, 64, 0, stream>>>(bsum, ptr, nb, N);
    scan_add_kernel<<<(N + B - 1) / B, B, 0, stream>>>(ptr, bsum, cnt, N);
    sort_kernel<<<(E + B - 1) / B, B, 0, stream>>>(row, col, ew, dinv, cnt, edat, E);

    premlp_xw_kernel<<<(ndThreads + B - 1) / B, B, 0, stream>>>(
        x, Wpre0, bpre0, Wpre1, bpre1, Wg[0], bufB, N);

    int nWaves = (N + 1) / 2;
    int gBlocks = (nWaves + 3) / 4;

    gather_kernel<false><<<gBlocks, 256, 0, stream>>>(
        bufB, edat, ptr, dinv, bg[0], Wg[1], bat, bufA, sums, gcnt, N);
    gather_kernel<false><<<gBlocks, 256, 0, stream>>>(
        bufA, edat, ptr, dinv, bg[1], Wg[2], bat, bufB, sums, gcnt, N);
    gather_kernel<true><<<gBlocks, 256, 0, stream>>>(
        bufB, edat, ptr, dinv, bg[2], nullptr, bat, nullptr, sums, gcnt, N);

    postmlp_kernel<<<(G + B - 1) / B, B, 0, stream>>>(sums, gcnt, Wpost0, bpost0, Wpost1, bpost1, out, G);
}